// Round 8
// baseline (525.980 us; speedup 1.0000x reference)
//
#include <hip/hip_runtime.h>

#define D 16
#define WPP 48          // W matrices resident in LDS per pass
#define MMBLK 512       // threads per mm block
#define MMGRID 512      // mm grid (2 blocks/CU on 256 CUs)

// ===========================================================================
// Sort-free LDS-W kernel. W is staged into LDS in ceil(NW/48) passes
// (rows padded to 80B so the 16-lane b128 read pattern is bank-conflict-free:
// float4 quad index = wloc*80 + o*5 + r; o*5 mod 8 distinct for o=0..7 ->
// 2-way aliasing only, which is free). Each pass re-scans this block's edge
// chunk; an edge is computed in exactly the pass holding its widx. Per edge:
// 16 lanes, lane o reads W row o from LDS, x row broadcast via __shfl
// (width 16), one 64B-line atomicAdd into out.
// ===========================================================================
__global__ __launch_bounds__(MMBLK) void mm_lds_kernel(
    const float* __restrict__ x, const float* __restrict__ W,
    const int* __restrict__ u, const int* __restrict__ v,
    const int* __restrict__ widx, float* __restrict__ out,
    int E, int NW) {
    __shared__ float4 sW4[WPP * 80];   // 48 mats * 16 rows * 20 floats = 60KB
    int t = threadIdx.x;
    int b = blockIdx.x;
    int o = t & 15;
    int g = t >> 4;                    // 32 edge-groups per block

    int chunk = (E + MMGRID - 1) / MMGRID;
    int cbeg = b * chunk;
    if (cbeg > E) cbeg = E;
    int cend = cbeg + chunk; if (cend > E) cend = E;

    const float4* W4 = (const float4*)W;

    for (int wbase = 0; wbase < NW; wbase += WPP) {
        int wcount = NW - wbase; if (wcount > WPP) wcount = WPP;

        // stage this pass's W slice into LDS (padded rows)
        __syncthreads();               // protect LDS from previous pass
        for (int idx = t; idx < wcount * 64; idx += MMBLK) {
            int mat = idx >> 6;
            int rem = idx & 63;        // rem = o*4 + i4
            int oo = rem >> 2;
            int i4 = rem & 3;
            sW4[mat * 80 + oo * 5 + i4] = W4[((size_t)(wbase + mat) << 6) + rem];
        }
        __syncthreads();

        int wlim = wbase + wcount;
        for (int e = cbeg + g; e < cend; e += 32) {
            int w = widx[e];
            if (w >= wbase && w < wlim) {
                int uu = u[e];
                int vv = v[e];
                float xv = x[((size_t)uu << 4) + o];
                int base = (w - wbase) * 80 + o * 5;
                float4 w0 = sW4[base + 0];
                float4 w1 = sW4[base + 1];
                float4 w2 = sW4[base + 2];
                float4 w3 = sW4[base + 3];
                float a = 0.0f;
                a += w0.x * __shfl(xv,  0, 16);
                a += w0.y * __shfl(xv,  1, 16);
                a += w0.z * __shfl(xv,  2, 16);
                a += w0.w * __shfl(xv,  3, 16);
                a += w1.x * __shfl(xv,  4, 16);
                a += w1.y * __shfl(xv,  5, 16);
                a += w1.z * __shfl(xv,  6, 16);
                a += w1.w * __shfl(xv,  7, 16);
                a += w2.x * __shfl(xv,  8, 16);
                a += w2.y * __shfl(xv,  9, 16);
                a += w2.z * __shfl(xv, 10, 16);
                a += w2.w * __shfl(xv, 11, 16);
                a += w3.x * __shfl(xv, 12, 16);
                a += w3.y * __shfl(xv, 13, 16);
                a += w3.z * __shfl(xv, 14, 16);
                a += w3.w * __shfl(xv, 15, 16);
                atomicAdd(out + ((size_t)vv << 4) + o, a);
            }
        }
    }
}

__global__ __launch_bounds__(256) void relu_kernel(float* __restrict__ out, int n4) {
    int i = blockIdx.x * 256 + threadIdx.x;
    if (i >= n4) return;
    float4* p = (float4*)out + i;
    float4 val = *p;
    val.x = fmaxf(val.x, 0.0f);
    val.y = fmaxf(val.y, 0.0f);
    val.z = fmaxf(val.z, 0.0f);
    val.w = fmaxf(val.w, 0.0f);
    *p = val;
}

// Fallback: original edge-parallel atomic path (per-edge W fetch from cache).
__global__ __launch_bounds__(256) void edge_scatter_kernel(
    const float* __restrict__ x, const float* __restrict__ W,
    const int* __restrict__ u, const int* __restrict__ v,
    const int* __restrict__ widx, float* __restrict__ out, int E) {
    int tid = blockIdx.x * 256 + threadIdx.x;
    int e = tid >> 4;
    int o = tid & 15;
    if (e >= E) return;
    int w = widx[e], uu = u[e], vv = v[e];
    const float* Wr = W + (size_t)w * (D * D) + (size_t)o * D;
    float4 w0 = *(const float4*)(Wr + 0);
    float4 w1 = *(const float4*)(Wr + 4);
    float4 w2 = *(const float4*)(Wr + 8);
    float4 w3 = *(const float4*)(Wr + 12);
    float xv = x[(size_t)uu * D + o];
    float acc = 0.0f;
    acc += w0.x * __shfl(xv,  0, 16);
    acc += w0.y * __shfl(xv,  1, 16);
    acc += w0.z * __shfl(xv,  2, 16);
    acc += w0.w * __shfl(xv,  3, 16);
    acc += w1.x * __shfl(xv,  4, 16);
    acc += w1.y * __shfl(xv,  5, 16);
    acc += w1.z * __shfl(xv,  6, 16);
    acc += w1.w * __shfl(xv,  7, 16);
    acc += w2.x * __shfl(xv,  8, 16);
    acc += w2.y * __shfl(xv,  9, 16);
    acc += w2.z * __shfl(xv, 10, 16);
    acc += w2.w * __shfl(xv, 11, 16);
    acc += w3.x * __shfl(xv, 12, 16);
    acc += w3.y * __shfl(xv, 13, 16);
    acc += w3.z * __shfl(xv, 14, 16);
    acc += w3.w * __shfl(xv, 15, 16);
    atomicAdd(out + (size_t)vv * D + o, acc);
}

extern "C" void kernel_launch(void* const* d_in, const int* in_sizes, int n_in,
                              void* d_out, int out_size, void* d_ws, size_t ws_size,
                              hipStream_t stream) {
    const float* x    = (const float*)d_in[0];
    const float* W    = (const float*)d_in[1];
    const int*   u    = (const int*)d_in[2];
    const int*   v    = (const int*)d_in[3];
    const int*   widx = (const int*)d_in[4];
    float* out = (float*)d_out;

    int E  = in_sizes[2];
    int NW = in_sizes[1] / (D * D);
    int n4 = out_size / 4;

    // out is poisoned before each timed run; atomics need a zero base.
    (void)hipMemsetAsync(d_out, 0, (size_t)out_size * sizeof(float), stream);

    if ((out_size % D) == 0 && E > 0) {
        mm_lds_kernel<<<MMGRID, MMBLK, 0, stream>>>(x, W, u, v, widx, out, E, NW);
    } else if (E > 0) {
        int total_threads = E * 16;
        int blocks = (total_threads + 255) / 256;
        edge_scatter_kernel<<<blocks, 256, 0, stream>>>(x, W, u, v, widx, out, E);
    }

    int rblocks = (n4 + 255) / 256;
    relu_kernel<<<rblocks, 256, 0, stream>>>(out, n4);
}